// Round 12
// baseline (343.632 us; speedup 1.0000x reference)
//
#include <hip/hip_runtime.h>

#define H 128
#define NHEADS 8
#define SQ 4096
#define HD 1024   // NHEADS*H

typedef float f32x4 __attribute__((ext_vector_type(4)));
typedef __bf16 bf16x8 __attribute__((ext_vector_type(8)));
typedef unsigned short u16x4 __attribute__((ext_vector_type(4)));
typedef unsigned short u16x8 __attribute__((ext_vector_type(8)));

static __device__ __forceinline__ unsigned short f2bf(float f) {
  unsigned int u = __builtin_bit_cast(unsigned int, f);
  u += 0x7fffu + ((u >> 16) & 1u);           // round-nearest-even
  return (unsigned short)(u >> 16);
}
static __device__ __forceinline__ float b2f(unsigned short s) {
  unsigned int u = (unsigned int)s << 16;
  return __builtin_bit_cast(float, u);
}
static __device__ __forceinline__ bf16x8 ld_bf8(const unsigned short* p) {
  return __builtin_bit_cast(bf16x8, *(const u16x8*)p);
}

// ---------------- kernel 0: weight transpose+convert (R11 verbatim) -------
__global__ __launch_bounds__(256) void prep_kernel(
    const float* __restrict__ W1, const float* __restrict__ W2,
    const float* __restrict__ Wc,
    unsigned short* __restrict__ W1T, unsigned short* __restrict__ W2T,
    unsigned short* __restrict__ WcT)
{
  __shared__ unsigned short tile[64 * 66];
  const int b = blockIdx.x, tid = threadIdx.x;
  if (b < 32) {
    const int k0 = (b & 1) * 64, n0 = (b >> 1) * 64;
    for (int i = 0; i < 16; ++i) {
      int idx = tid + i * 256;
      int r = idx >> 6, cc = idx & 63;
      tile[cc * 66 + r] = f2bf(W1[(size_t)(k0 + r) * HD + n0 + cc]);
    }
    __syncthreads();
    for (int i = 0; i < 16; ++i) {
      int idx = tid + i * 256;
      int r = idx >> 6, cc = idx & 63;
      W1T[(size_t)(n0 + r) * H + k0 + cc] = tile[r * 66 + cc];
    }
    __syncthreads();
    for (int i = 0; i < 16; ++i) {
      int idx = tid + i * 256;
      int r = idx >> 6, cc = idx & 63;
      tile[cc * 66 + r] = f2bf(W2[(size_t)(k0 + r) * HD + n0 + cc]);
    }
    __syncthreads();
    for (int i = 0; i < 16; ++i) {
      int idx = tid + i * 256;
      int r = idx >> 6, cc = idx & 63;
      W2T[(size_t)(n0 + r) * H + k0 + cc] = tile[r * 66 + cc];
    }
  } else {
    const int bb = b - 32;
    const int n0 = (bb & 1) * 64, k0 = (bb >> 1) * 64;
    for (int i = 0; i < 16; ++i) {
      int idx = tid + i * 256;
      int r = idx >> 6, cc = idx & 63;
      tile[cc * 66 + r] = f2bf(Wc[(size_t)(k0 + r) * H + n0 + cc]);
    }
    __syncthreads();
    for (int i = 0; i < 16; ++i) {
      int idx = tid + i * 256;
      int r = idx >> 6, cc = idx & 63;
      WcT[(size_t)(n0 + r) * HD + k0 + cc] = tile[r * 66 + cc];
    }
  }
}

// ---------------- kernel 1: q1/q2 projection (R11 verbatim) ---------------
__global__ __launch_bounds__(256) void proj_kernel(
    const float* __restrict__ x,
    const float* __restrict__ b1, const float* __restrict__ b2,
    const unsigned short* __restrict__ W1T, const unsigned short* __restrict__ W2T,
    unsigned short* __restrict__ q1bf, unsigned short* __restrict__ q2K,
    unsigned short* __restrict__ q2VT)
{
  __shared__ unsigned short At[64 * 136];
  __shared__ unsigned short Bt[128 * 136];
  const int tid = threadIdx.x;
  const int st = blockIdx.x & 63, h = blockIdx.x >> 6;
  const int s0 = st * 64;
  const int lane = tid & 63, w = tid >> 6;
  const int c = lane & 15, q4 = lane >> 4;

  for (int i = 0; i < 4; ++i) {
    int ch = tid + i * 256;
    int row = ch >> 4, col8 = (ch & 15) * 8;
    const float* gp = x + (s0 + row) * H + col8;
    f32x4 a = *(const f32x4*)gp;
    f32x4 b = *(const f32x4*)(gp + 4);
    u16x8 v;
    v[0]=f2bf(a[0]); v[1]=f2bf(a[1]); v[2]=f2bf(a[2]); v[3]=f2bf(a[3]);
    v[4]=f2bf(b[0]); v[5]=f2bf(b[1]); v[6]=f2bf(b[2]); v[7]=f2bf(b[3]);
    *(u16x8*)&At[row * 136 + col8] = v;
  }
  for (int i = 0; i < 8; ++i) {
    int ch = tid + i * 256;
    int row = ch >> 4, col8 = (ch & 15) * 8;
    *(u16x8*)&Bt[row * 136 + col8] = *(const u16x8*)&W1T[(h * H + row) * H + col8];
  }
  __syncthreads();                           // S1

  bf16x8 af[4];
  for (int kc = 0; kc < 4; ++kc)
    af[kc] = ld_bf8(&At[(w * 16 + c) * 136 + kc * 32 + q4 * 8]);
  __syncthreads();                           // S2

  for (int nt = 0; nt < 8; ++nt) {
    f32x4 acc = {0.f, 0.f, 0.f, 0.f};
    for (int kc = 0; kc < 4; ++kc) {
      bf16x8 bf = ld_bf8(&Bt[(nt * 16 + c) * 136 + kc * 32 + q4 * 8]);
      acc = __builtin_amdgcn_mfma_f32_16x16x32_bf16(af[kc], bf, acc, 0, 0, 0);
    }
    float bb = b1[h * H + nt * 16 + c];
    for (int r = 0; r < 4; ++r)
      At[(w * 16 + q4 * 4 + r) * 136 + nt * 16 + c] = f2bf(acc[r] + bb);
  }
  __syncthreads();                           // S3

  for (int i = 0; i < 4; ++i) {
    int ch = tid + i * 256;
    int row = ch >> 4, col8 = (ch & 15) * 8;
    *(u16x8*)&q1bf[(size_t)(h * SQ + s0 + row) * H + col8] =
        *(const u16x8*)&At[row * 136 + col8];
  }
  for (int i = 0; i < 8; ++i) {
    int ch = tid + i * 256;
    int row = ch >> 4, col8 = (ch & 15) * 8;
    *(u16x8*)&Bt[row * 136 + col8] = *(const u16x8*)&W2T[(h * H + row) * H + col8];
  }
  __syncthreads();                           // S4

  f32x4 q2a[8];
  for (int nt = 0; nt < 8; ++nt) {
    f32x4 acc = {0.f, 0.f, 0.f, 0.f};
    for (int kc = 0; kc < 4; ++kc) {
      bf16x8 bf = ld_bf8(&Bt[(nt * 16 + c) * 136 + kc * 32 + q4 * 8]);
      acc = __builtin_amdgcn_mfma_f32_16x16x32_bf16(af[kc], bf, acc, 0, 0, 0);
    }
    q2a[nt] = acc;
  }
  __syncthreads();                           // S5

  for (int nt = 0; nt < 8; ++nt) {
    float bb = b2[h * H + nt * 16 + c];
    unsigned short vs[4];
    for (int r = 0; r < 4; ++r) {
      unsigned short u = f2bf(q2a[nt][r] + bb);
      At[(w * 16 + q4 * 4 + r) * 136 + nt * 16 + c] = u;
      vs[r] = u;
    }
    u16x4 v4 = {vs[0], vs[1], vs[2], vs[3]};
    *(u16x4*)&Bt[(nt * 16 + c) * 72 + w * 16 + q4 * 4] = v4;
  }
  __syncthreads();                           // S6

  for (int i = 0; i < 4; ++i) {
    int ch = tid + i * 256;
    int row = ch >> 4, col8 = (ch & 15) * 8;
    *(u16x8*)&q2K[(size_t)(h * SQ + s0 + row) * H + col8] =
        *(const u16x8*)&At[row * 136 + col8];
  }
  for (int i = 0; i < 4; ++i) {
    int ch = tid + i * 256;
    int row = ch >> 3, col8 = (ch & 7) * 8;
    *(u16x8*)&q2VT[(size_t)(h * H + row) * SQ + s0 + col8] =
        *(const u16x8*)&Bt[row * 72 + col8];
  }
}

// ---------------- kernel 2: flash attention, NKB-way KEY-SPLIT ------------
// Template NKB (compile-time: R9's runtime-nkb VGPR lesson). grid 256*NKB.
// NKB=3: tiles 22/21/21, LDS 54272 B -> 3 blocks/CU (162816 <= 163840).
// NKB=2: R10-proven config (32/32 tiles, 2 blocks/CU).
// Pitch changes vs R10 (both pattern-proven elsewhere): Kt 152->136 (same
// form as proj Bt, proven), VT 88->72 (same form as R1 flash VT, proven).
// Pb stays 72. All pitches %8==0 (ds b64/b128 16B alignment -- R6 lesson).
template<int NKB>
__global__ __launch_bounds__(256, NKB) void flash_kernel(
    const unsigned short* __restrict__ q1bf,
    const unsigned short* __restrict__ q2K,
    const unsigned short* __restrict__ q2VT,
    unsigned short* __restrict__ ctxp,   // [kb][s][h*128+d] bf16, local-normed
    float* __restrict__ lbuf)            // [kb][h][s]
{
  __shared__ unsigned short Kt[64 * 136];      // [key][d]  pitch 136 (17408 B)
  __shared__ unsigned short VT[128 * 72];      // [d][key]  pitch 72  (18432 B)
  __shared__ unsigned short Pb[4][2][16 * 72]; // per-wave/per-qblk   (18432 B)
  const int tid = threadIdx.x;
  const int bid = blockIdx.x;
  const int kb = bid >> 8;                     // key slice
  const int h = (bid >> 5) & 7, qb = bid & 31;
  const int s0 = qb * 128;
  const int ntiles = (NKB == 2) ? 32 : (kb == 0 ? 22 : 21);
  const int kbase = (NKB == 2) ? kb * 2048
                               : (kb == 0 ? 0 : 1408 + (kb - 1) * 1344);
  const int lane = tid & 63, w = tid >> 6;
  const int c = lane & 15, q4 = lane >> 4;

  bf16x8 qf[2][4];
  for (int blk = 0; blk < 2; ++blk)
    for (int kc = 0; kc < 4; ++kc)
      qf[blk][kc] = ld_bf8(
          &q1bf[(h * SQ + s0 + w * 32 + blk * 16 + c) * H + kc * 32 + q4 * 8]);

  f32x4 acc[2][8];
  for (int blk = 0; blk < 2; ++blk)
    for (int nt = 0; nt < 8; ++nt) acc[blk][nt] = (f32x4){0.f, 0.f, 0.f, 0.f};
  float lsum[2] = {0.f, 0.f};

  u16x8 kreg[4], vreg[4];
  for (int i = 0; i < 4; ++i) {
    int ch = tid + i * 256;
    kreg[i] = *(const u16x8*)&q2K[(h * SQ + kbase + (ch >> 4)) * H + (ch & 15) * 8];
    vreg[i] = *(const u16x8*)&q2VT[(h * H + (ch >> 3)) * SQ + kbase + (ch & 7) * 8];
  }

  for (int kt = 0; kt < ntiles; ++kt) {
    if (kt) __syncthreads();               // prev-iter readers done
    for (int i = 0; i < 4; ++i) {          // regs -> LDS
      int ch = tid + i * 256;
      *(u16x8*)&Kt[(ch >> 4) * 136 + (ch & 15) * 8] = kreg[i];
      *(u16x8*)&VT[(ch >> 3) * 72 + (ch & 7) * 8] = vreg[i];
    }
    __syncthreads();                       // staging visible

    if (kt < ntiles - 1) {                 // prefetch next tile -> regs
      const int k0 = kbase + (kt + 1) * 64;
      for (int i = 0; i < 4; ++i) {
        int ch = tid + i * 256;
        kreg[i] = *(const u16x8*)&q2K[(h * SQ + k0 + (ch >> 4)) * H + (ch & 15) * 8];
        vreg[i] = *(const u16x8*)&q2VT[(h * H + (ch >> 3)) * SQ + k0 + (ch & 7) * 8];
      }
    }

    // S^T = K.Q^T per q-block: C[key = mt*16 + q4*4 + r][q = c]
    f32x4 sc[2][4];
    for (int mt = 0; mt < 4; ++mt) {
      bf16x8 kf[4];
      for (int kc = 0; kc < 4; ++kc)
        kf[kc] = ld_bf8(&Kt[(mt * 16 + c) * 136 + kc * 32 + q4 * 8]);
      for (int blk = 0; blk < 2; ++blk) {
        f32x4 s = {0.f, 0.f, 0.f, 0.f};
        for (int kc = 0; kc < 4; ++kc)
          s = __builtin_amdgcn_mfma_f32_16x16x32_bf16(kf[kc], qf[blk][kc], s, 0, 0, 0);
        sc[blk][mt] = s;
      }
    }

    // p = exp(s); per-lane partial l; write P row-major [q = c][key]
    for (int blk = 0; blk < 2; ++blk) {
      float ts = 0.f;
      for (int mt = 0; mt < 4; ++mt) {
        f32x4 p;
        for (int r = 0; r < 4; ++r) { p[r] = __expf(sc[blk][mt][r]); ts += p[r]; }
        sc[blk][mt] = p;
      }
      lsum[blk] += ts;
      for (int mt = 0; mt < 4; ++mt) {
        u16x4 pv = {f2bf(sc[blk][mt][0]), f2bf(sc[blk][mt][1]),
                    f2bf(sc[blk][mt][2]), f2bf(sc[blk][mt][3])};
        *(u16x4*)&Pb[w][blk][c * 72 + mt * 16 + q4 * 4] = pv;
      }
    }

    // PV: acc[blk][nt] += P[q][key32] . V[key32][d]; vf shared across blks
    for (int kc2 = 0; kc2 < 2; ++kc2) {
      bf16x8 pf0 = ld_bf8(&Pb[w][0][c * 72 + kc2 * 32 + q4 * 8]);
      bf16x8 pf1 = ld_bf8(&Pb[w][1][c * 72 + kc2 * 32 + q4 * 8]);
      for (int nt = 0; nt < 8; ++nt) {
        bf16x8 vf = ld_bf8(&VT[(nt * 16 + c) * 72 + kc2 * 32 + q4 * 8]);
        acc[0][nt] = __builtin_amdgcn_mfma_f32_16x16x32_bf16(pf0, vf, acc[0][nt], 0, 0, 0);
        acc[1][nt] = __builtin_amdgcn_mfma_f32_16x16x32_bf16(pf1, vf, acc[1][nt], 0, 0, 0);
      }
    }
  }

  // epilogue: merge l across q4-groups; store local-normalized O + l
  unsigned short* ctxk = ctxp + (size_t)kb * SQ * HD;
  for (int blk = 0; blk < 2; ++blk) {
    float l = lsum[blk];
    l += __shfl_xor(l, 16);
    l += __shfl_xor(l, 32);
    float rl = 1.f / l;                    // valid for q = c
    if (q4 == 0)
      lbuf[(size_t)kb * NHEADS * SQ + h * SQ + s0 + w * 32 + blk * 16 + c] = l;
    float r0 = __shfl(rl, q4 * 4 + 0);
    float r1 = __shfl(rl, q4 * 4 + 1);
    float r2 = __shfl(rl, q4 * 4 + 2);
    float r3 = __shfl(rl, q4 * 4 + 3);
    for (int nt = 0; nt < 8; ++nt) {
      int col = h * H + nt * 16 + c;
      int srow = s0 + w * 32 + blk * 16 + q4 * 4;
      ctxk[(size_t)(srow + 0) * HD + col] = f2bf(acc[blk][nt][0] * r0);
      ctxk[(size_t)(srow + 1) * HD + col] = f2bf(acc[blk][nt][1] * r1);
      ctxk[(size_t)(srow + 2) * HD + col] = f2bf(acc[blk][nt][2] * r2);
      ctxk[(size_t)(srow + 3) * HD + col] = f2bf(acc[blk][nt][3] * r3);
    }
  }
}

// ---------------- kernel 3: out = combine(ctxp) @ Wc + bc + x -------------
// R9/R10-validated grid-64 structure; A-tile staging combines the NKB
// key-slice partials (head kt => NKB scalar l-loads per row; exact for
// raw-exp softmax).
template<int NKB>
__global__ __launch_bounds__(256) void out_kernel(
    const unsigned short* __restrict__ ctxp,
    const float* __restrict__ lbuf,
    const unsigned short* __restrict__ WcT,
    const float* __restrict__ bc,
    const float* __restrict__ x,
    float* __restrict__ out)
{
  __shared__ unsigned short At[64 * 136];
  __shared__ unsigned short Bt[128 * 136];
  const int tid = threadIdx.x;
  const int s0 = blockIdx.x * 64;
  const int lane = tid & 63, w = tid >> 6;
  const int c = lane & 15, q4 = lane >> 4;

  f32x4 acc[8];
  for (int nt = 0; nt < 8; ++nt) acc[nt] = (f32x4){0.f, 0.f, 0.f, 0.f};

  for (int kt = 0; kt < 8; ++kt) {         // head kt
    __syncthreads();
    for (int i = 0; i < 4; ++i) {
      int ch = tid + i * 256;
      int row = ch >> 4, col8 = (ch & 15) * 8;
      const unsigned short* p0 = &ctxp[(size_t)(s0 + row) * HD + kt * 128 + col8];
      float lv[NKB], lsum = 0.f;
      for (int kb = 0; kb < NKB; ++kb) {
        lv[kb] = lbuf[(size_t)kb * NHEADS * SQ + (size_t)kt * SQ + s0 + row];
        lsum += lv[kb];
      }
      float ri = 1.f / lsum;
      float fv[8];
      for (int e = 0; e < 8; ++e) fv[e] = 0.f;
      for (int kb = 0; kb < NKB; ++kb) {
        u16x8 a = *(const u16x8*)(p0 + (size_t)kb * SQ * HD);
        float wgt = lv[kb] * ri;
        for (int e = 0; e < 8; ++e) fv[e] += wgt * b2f(a[e]);
      }
      u16x8 av;
      for (int e = 0; e < 8; ++e) av[e] = f2bf(fv[e]);
      *(u16x8*)&At[row * 136 + col8] = av;
    }
    for (int i = 0; i < 8; ++i) {
      int ch = tid + i * 256;
      int row = ch >> 4, col8 = (ch & 15) * 8;
      *(u16x8*)&Bt[row * 136 + col8] =
          *(const u16x8*)&WcT[row * HD + kt * 128 + col8];
    }
    __syncthreads();
    bf16x8 af[4];
    for (int kc = 0; kc < 4; ++kc)
      af[kc] = ld_bf8(&At[(w * 16 + c) * 136 + kc * 32 + q4 * 8]);
    for (int nt = 0; nt < 8; ++nt) {
      f32x4 a = acc[nt];
      for (int kc = 0; kc < 4; ++kc) {
        bf16x8 bf = ld_bf8(&Bt[(nt * 16 + c) * 136 + kc * 32 + q4 * 8]);
        a = __builtin_amdgcn_mfma_f32_16x16x32_bf16(af[kc], bf, a, 0, 0, 0);
      }
      acc[nt] = a;
    }
  }
  for (int nt = 0; nt < 8; ++nt) {
    float bb = bc[nt * 16 + c];
    for (int r = 0; r < 4; ++r) {
      int srow = s0 + w * 16 + q4 * 4 + r;
      int col = nt * 16 + c;
      out[srow * H + col] = acc[nt][r] + bb + x[srow * H + col];
    }
  }
}

extern "C" void kernel_launch(void* const* d_in, const int* in_sizes, int n_in,
                              void* d_out, int out_size, void* d_ws, size_t ws_size,
                              hipStream_t stream) {
  const float* x  = (const float*)d_in[0];
  const float* W1 = (const float*)d_in[1];
  const float* b1 = (const float*)d_in[2];
  const float* W2 = (const float*)d_in[3];
  const float* b2 = (const float*)d_in[4];
  const float* Wc = (const float*)d_in[5];
  const float* bc = (const float*)d_in[6];
  float* out = (float*)d_out;

  // NKB=3 needs 51,511,296 B; NKB=2 needs 42,991,616 B (proven R9/R10).
  // ws_size is launch-invariant -> nkb constant across calls (capture-safe).
  const size_t NEED3 = (size_t)3 * NHEADS * SQ * H * 2
                     + (size_t)3 * SQ * HD * 2
                     + (size_t)3 * NHEADS * SQ * 4
                     + (size_t)3 * HD * H * 2;
  const int nkb = (ws_size >= NEED3) ? 3 : 2;

  char* ws = (char*)d_ws;
  unsigned short* q1bf = (unsigned short*)ws; ws += (size_t)NHEADS * SQ * H * 2;
  unsigned short* q2K  = (unsigned short*)ws; ws += (size_t)NHEADS * SQ * H * 2;
  unsigned short* q2VT = (unsigned short*)ws; ws += (size_t)NHEADS * SQ * H * 2;
  unsigned short* ctxp = (unsigned short*)ws; ws += (size_t)nkb * SQ * HD * 2;
  float*          lbuf = (float*)ws;          ws += (size_t)nkb * NHEADS * SQ * 4;
  unsigned short* W1T  = (unsigned short*)ws; ws += (size_t)HD * H * 2;
  unsigned short* W2T  = (unsigned short*)ws; ws += (size_t)HD * H * 2;
  unsigned short* WcT  = (unsigned short*)ws; ws += (size_t)HD * H * 2;

  prep_kernel<<<64, 256, 0, stream>>>(W1, W2, Wc, W1T, W2T, WcT);
  proj_kernel<<<512, 256, 0, stream>>>(x, b1, b2, W1T, W2T, q1bf, q2K, q2VT);
  if (nkb == 3) {
    flash_kernel<3><<<768, 256, 0, stream>>>(q1bf, q2K, q2VT, ctxp, lbuf);
    out_kernel<3><<<64, 256, 0, stream>>>(ctxp, lbuf, WcT, bc, x, out);
  } else {
    flash_kernel<2><<<512, 256, 0, stream>>>(q1bf, q2K, q2VT, ctxp, lbuf);
    out_kernel<2><<<64, 256, 0, stream>>>(ctxp, lbuf, WcT, bc, x, out);
  }
}

// Round 13
// 215.367 us; speedup vs baseline: 1.5956x; 1.5956x over previous
//
#include <hip/hip_runtime.h>

#define H 128
#define NHEADS 8
#define SQ 4096
#define HD 1024   // NHEADS*H

typedef float f32x4 __attribute__((ext_vector_type(4)));
typedef __bf16 bf16x8 __attribute__((ext_vector_type(8)));
typedef unsigned short u16x4 __attribute__((ext_vector_type(4)));
typedef unsigned short u16x8 __attribute__((ext_vector_type(8)));

static __device__ __forceinline__ unsigned short f2bf(float f) {
  unsigned int u = __builtin_bit_cast(unsigned int, f);
  u += 0x7fffu + ((u >> 16) & 1u);           // round-nearest-even
  return (unsigned short)(u >> 16);
}
static __device__ __forceinline__ float b2f(unsigned short s) {
  unsigned int u = (unsigned int)s << 16;
  return __builtin_bit_cast(float, u);
}
static __device__ __forceinline__ bf16x8 ld_bf8(const unsigned short* p) {
  return __builtin_bit_cast(bf16x8, *(const u16x8*)p);
}

// ---------------- kernel 0: weight transpose+convert (R11 verbatim) -------
__global__ __launch_bounds__(256) void prep_kernel(
    const float* __restrict__ W1, const float* __restrict__ W2,
    const float* __restrict__ Wc,
    unsigned short* __restrict__ W1T, unsigned short* __restrict__ W2T,
    unsigned short* __restrict__ WcT)
{
  __shared__ unsigned short tile[64 * 66];
  const int b = blockIdx.x, tid = threadIdx.x;
  if (b < 32) {
    const int k0 = (b & 1) * 64, n0 = (b >> 1) * 64;
    for (int i = 0; i < 16; ++i) {
      int idx = tid + i * 256;
      int r = idx >> 6, cc = idx & 63;
      tile[cc * 66 + r] = f2bf(W1[(size_t)(k0 + r) * HD + n0 + cc]);
    }
    __syncthreads();
    for (int i = 0; i < 16; ++i) {
      int idx = tid + i * 256;
      int r = idx >> 6, cc = idx & 63;
      W1T[(size_t)(n0 + r) * H + k0 + cc] = tile[r * 66 + cc];
    }
    __syncthreads();
    for (int i = 0; i < 16; ++i) {
      int idx = tid + i * 256;
      int r = idx >> 6, cc = idx & 63;
      tile[cc * 66 + r] = f2bf(W2[(size_t)(k0 + r) * HD + n0 + cc]);
    }
    __syncthreads();
    for (int i = 0; i < 16; ++i) {
      int idx = tid + i * 256;
      int r = idx >> 6, cc = idx & 63;
      W2T[(size_t)(n0 + r) * H + k0 + cc] = tile[r * 66 + cc];
    }
  } else {
    const int bb = b - 32;
    const int n0 = (bb & 1) * 64, k0 = (bb >> 1) * 64;
    for (int i = 0; i < 16; ++i) {
      int idx = tid + i * 256;
      int r = idx >> 6, cc = idx & 63;
      tile[cc * 66 + r] = f2bf(Wc[(size_t)(k0 + r) * H + n0 + cc]);
    }
    __syncthreads();
    for (int i = 0; i < 16; ++i) {
      int idx = tid + i * 256;
      int r = idx >> 6, cc = idx & 63;
      WcT[(size_t)(n0 + r) * HD + k0 + cc] = tile[r * 66 + cc];
    }
  }
}

// ---------------- kernel 1: q1/q2 projection (R11 verbatim) ---------------
__global__ __launch_bounds__(256) void proj_kernel(
    const float* __restrict__ x,
    const float* __restrict__ b1, const float* __restrict__ b2,
    const unsigned short* __restrict__ W1T, const unsigned short* __restrict__ W2T,
    unsigned short* __restrict__ q1bf, unsigned short* __restrict__ q2K,
    unsigned short* __restrict__ q2VT)
{
  __shared__ unsigned short At[64 * 136];
  __shared__ unsigned short Bt[128 * 136];
  const int tid = threadIdx.x;
  const int st = blockIdx.x & 63, h = blockIdx.x >> 6;
  const int s0 = st * 64;
  const int lane = tid & 63, w = tid >> 6;
  const int c = lane & 15, q4 = lane >> 4;

  for (int i = 0; i < 4; ++i) {
    int ch = tid + i * 256;
    int row = ch >> 4, col8 = (ch & 15) * 8;
    const float* gp = x + (s0 + row) * H + col8;
    f32x4 a = *(const f32x4*)gp;
    f32x4 b = *(const f32x4*)(gp + 4);
    u16x8 v;
    v[0]=f2bf(a[0]); v[1]=f2bf(a[1]); v[2]=f2bf(a[2]); v[3]=f2bf(a[3]);
    v[4]=f2bf(b[0]); v[5]=f2bf(b[1]); v[6]=f2bf(b[2]); v[7]=f2bf(b[3]);
    *(u16x8*)&At[row * 136 + col8] = v;
  }
  for (int i = 0; i < 8; ++i) {
    int ch = tid + i * 256;
    int row = ch >> 4, col8 = (ch & 15) * 8;
    *(u16x8*)&Bt[row * 136 + col8] = *(const u16x8*)&W1T[(h * H + row) * H + col8];
  }
  __syncthreads();                           // S1

  bf16x8 af[4];
  for (int kc = 0; kc < 4; ++kc)
    af[kc] = ld_bf8(&At[(w * 16 + c) * 136 + kc * 32 + q4 * 8]);
  __syncthreads();                           // S2

  for (int nt = 0; nt < 8; ++nt) {
    f32x4 acc = {0.f, 0.f, 0.f, 0.f};
    for (int kc = 0; kc < 4; ++kc) {
      bf16x8 bf = ld_bf8(&Bt[(nt * 16 + c) * 136 + kc * 32 + q4 * 8]);
      acc = __builtin_amdgcn_mfma_f32_16x16x32_bf16(af[kc], bf, acc, 0, 0, 0);
    }
    float bb = b1[h * H + nt * 16 + c];
    for (int r = 0; r < 4; ++r)
      At[(w * 16 + q4 * 4 + r) * 136 + nt * 16 + c] = f2bf(acc[r] + bb);
  }
  __syncthreads();                           // S3

  for (int i = 0; i < 4; ++i) {
    int ch = tid + i * 256;
    int row = ch >> 4, col8 = (ch & 15) * 8;
    *(u16x8*)&q1bf[(size_t)(h * SQ + s0 + row) * H + col8] =
        *(const u16x8*)&At[row * 136 + col8];
  }
  for (int i = 0; i < 8; ++i) {
    int ch = tid + i * 256;
    int row = ch >> 4, col8 = (ch & 15) * 8;
    *(u16x8*)&Bt[row * 136 + col8] = *(const u16x8*)&W2T[(h * H + row) * H + col8];
  }
  __syncthreads();                           // S4

  f32x4 q2a[8];
  for (int nt = 0; nt < 8; ++nt) {
    f32x4 acc = {0.f, 0.f, 0.f, 0.f};
    for (int kc = 0; kc < 4; ++kc) {
      bf16x8 bf = ld_bf8(&Bt[(nt * 16 + c) * 136 + kc * 32 + q4 * 8]);
      acc = __builtin_amdgcn_mfma_f32_16x16x32_bf16(af[kc], bf, acc, 0, 0, 0);
    }
    q2a[nt] = acc;
  }
  __syncthreads();                           // S5

  for (int nt = 0; nt < 8; ++nt) {
    float bb = b2[h * H + nt * 16 + c];
    unsigned short vs[4];
    for (int r = 0; r < 4; ++r) {
      unsigned short u = f2bf(q2a[nt][r] + bb);
      At[(w * 16 + q4 * 4 + r) * 136 + nt * 16 + c] = u;
      vs[r] = u;
    }
    u16x4 v4 = {vs[0], vs[1], vs[2], vs[3]};
    *(u16x4*)&Bt[(nt * 16 + c) * 72 + w * 16 + q4 * 4] = v4;
  }
  __syncthreads();                           // S6

  for (int i = 0; i < 4; ++i) {
    int ch = tid + i * 256;
    int row = ch >> 4, col8 = (ch & 15) * 8;
    *(u16x8*)&q2K[(size_t)(h * SQ + s0 + row) * H + col8] =
        *(const u16x8*)&At[row * 136 + col8];
  }
  for (int i = 0; i < 4; ++i) {
    int ch = tid + i * 256;
    int row = ch >> 3, col8 = (ch & 7) * 8;
    *(u16x8*)&q2VT[(size_t)(h * H + row) * SQ + s0 + col8] =
        *(const u16x8*)&Bt[row * 72 + col8];
  }
}

// ---------------- kernel 2: flash attention, NKB-way KEY-SPLIT ------------
// grid 256*NKB; LDS 54272 B (Kt 136 / VT 72 / Pb 72 -- all quad-uniform for
// b128 staging+frag access, all %8==0 for 16B DS alignment).
// __launch_bounds__(256, 2) ALWAYS: R12's (256,3) made the allocator chase a
// 6-wave tier (VGPR 84) and spill the 64-VGPR accumulator to scratch
// (WRITE_SIZE 16->150 MB, flash 98->228 us). The 2nd arg is an allocator
// floor, not a residency cap: at VGPR~128, 3 blocks/CU co-reside anyway
// (3 x 54272 = 162816 <= 163840 LDS; 3 x 4 x 128 = 1536 <= 2048 VGPR-waves).
template<int NKB>
__global__ __launch_bounds__(256, 2) void flash_kernel(
    const unsigned short* __restrict__ q1bf,
    const unsigned short* __restrict__ q2K,
    const unsigned short* __restrict__ q2VT,
    unsigned short* __restrict__ ctxp,   // [kb][s][h*128+d] bf16, local-normed
    float* __restrict__ lbuf)            // [kb][h][s]
{
  __shared__ unsigned short Kt[64 * 136];      // [key][d]  pitch 136 (17408 B)
  __shared__ unsigned short VT[128 * 72];      // [d][key]  pitch 72  (18432 B)
  __shared__ unsigned short Pb[4][2][16 * 72]; // per-wave/per-qblk   (18432 B)
  const int tid = threadIdx.x;
  const int bid = blockIdx.x;
  const int kb = bid >> 8;                     // key slice
  const int h = (bid >> 5) & 7, qb = bid & 31;
  const int s0 = qb * 128;
  const int ntiles = (NKB == 2) ? 32 : (kb == 0 ? 22 : 21);
  const int kbase = (NKB == 2) ? kb * 2048
                               : (kb == 0 ? 0 : 1408 + (kb - 1) * 1344);
  const int lane = tid & 63, w = tid >> 6;
  const int c = lane & 15, q4 = lane >> 4;

  bf16x8 qf[2][4];
  for (int blk = 0; blk < 2; ++blk)
    for (int kc = 0; kc < 4; ++kc)
      qf[blk][kc] = ld_bf8(
          &q1bf[(h * SQ + s0 + w * 32 + blk * 16 + c) * H + kc * 32 + q4 * 8]);

  f32x4 acc[2][8];
  for (int blk = 0; blk < 2; ++blk)
    for (int nt = 0; nt < 8; ++nt) acc[blk][nt] = (f32x4){0.f, 0.f, 0.f, 0.f};
  float lsum[2] = {0.f, 0.f};

  u16x8 kreg[4], vreg[4];
  for (int i = 0; i < 4; ++i) {
    int ch = tid + i * 256;
    kreg[i] = *(const u16x8*)&q2K[(h * SQ + kbase + (ch >> 4)) * H + (ch & 15) * 8];
    vreg[i] = *(const u16x8*)&q2VT[(h * H + (ch >> 3)) * SQ + kbase + (ch & 7) * 8];
  }

  for (int kt = 0; kt < ntiles; ++kt) {
    if (kt) __syncthreads();               // prev-iter readers done
    for (int i = 0; i < 4; ++i) {          // regs -> LDS
      int ch = tid + i * 256;
      *(u16x8*)&Kt[(ch >> 4) * 136 + (ch & 15) * 8] = kreg[i];
      *(u16x8*)&VT[(ch >> 3) * 72 + (ch & 7) * 8] = vreg[i];
    }
    __syncthreads();                       // staging visible

    if (kt < ntiles - 1) {                 // prefetch next tile -> regs
      const int k0 = kbase + (kt + 1) * 64;
      for (int i = 0; i < 4; ++i) {
        int ch = tid + i * 256;
        kreg[i] = *(const u16x8*)&q2K[(h * SQ + k0 + (ch >> 4)) * H + (ch & 15) * 8];
        vreg[i] = *(const u16x8*)&q2VT[(h * H + (ch >> 3)) * SQ + k0 + (ch & 7) * 8];
      }
    }

    // S^T = K.Q^T per q-block: C[key = mt*16 + q4*4 + r][q = c]
    f32x4 sc[2][4];
    for (int mt = 0; mt < 4; ++mt) {
      bf16x8 kf[4];
      for (int kc = 0; kc < 4; ++kc)
        kf[kc] = ld_bf8(&Kt[(mt * 16 + c) * 136 + kc * 32 + q4 * 8]);
      for (int blk = 0; blk < 2; ++blk) {
        f32x4 s = {0.f, 0.f, 0.f, 0.f};
        for (int kc = 0; kc < 4; ++kc)
          s = __builtin_amdgcn_mfma_f32_16x16x32_bf16(kf[kc], qf[blk][kc], s, 0, 0, 0);
        sc[blk][mt] = s;
      }
    }

    // p = exp(s); per-lane partial l; write P row-major [q = c][key]
    for (int blk = 0; blk < 2; ++blk) {
      float ts = 0.f;
      for (int mt = 0; mt < 4; ++mt) {
        f32x4 p;
        for (int r = 0; r < 4; ++r) { p[r] = __expf(sc[blk][mt][r]); ts += p[r]; }
        sc[blk][mt] = p;
      }
      lsum[blk] += ts;
      for (int mt = 0; mt < 4; ++mt) {
        u16x4 pv = {f2bf(sc[blk][mt][0]), f2bf(sc[blk][mt][1]),
                    f2bf(sc[blk][mt][2]), f2bf(sc[blk][mt][3])};
        *(u16x4*)&Pb[w][blk][c * 72 + mt * 16 + q4 * 4] = pv;
      }
    }

    // PV: acc[blk][nt] += P[q][key32] . V[key32][d]; vf shared across blks
    for (int kc2 = 0; kc2 < 2; ++kc2) {
      bf16x8 pf0 = ld_bf8(&Pb[w][0][c * 72 + kc2 * 32 + q4 * 8]);
      bf16x8 pf1 = ld_bf8(&Pb[w][1][c * 72 + kc2 * 32 + q4 * 8]);
      for (int nt = 0; nt < 8; ++nt) {
        bf16x8 vf = ld_bf8(&VT[(nt * 16 + c) * 72 + kc2 * 32 + q4 * 8]);
        acc[0][nt] = __builtin_amdgcn_mfma_f32_16x16x32_bf16(pf0, vf, acc[0][nt], 0, 0, 0);
        acc[1][nt] = __builtin_amdgcn_mfma_f32_16x16x32_bf16(pf1, vf, acc[1][nt], 0, 0, 0);
      }
    }
  }

  // epilogue: merge l across q4-groups; store local-normalized O + l
  unsigned short* ctxk = ctxp + (size_t)kb * SQ * HD;
  for (int blk = 0; blk < 2; ++blk) {
    float l = lsum[blk];
    l += __shfl_xor(l, 16);
    l += __shfl_xor(l, 32);
    float rl = 1.f / l;                    // valid for q = c
    if (q4 == 0)
      lbuf[(size_t)kb * NHEADS * SQ + h * SQ + s0 + w * 32 + blk * 16 + c] = l;
    float r0 = __shfl(rl, q4 * 4 + 0);
    float r1 = __shfl(rl, q4 * 4 + 1);
    float r2 = __shfl(rl, q4 * 4 + 2);
    float r3 = __shfl(rl, q4 * 4 + 3);
    for (int nt = 0; nt < 8; ++nt) {
      int col = h * H + nt * 16 + c;
      int srow = s0 + w * 32 + blk * 16 + q4 * 4;
      ctxk[(size_t)(srow + 0) * HD + col] = f2bf(acc[blk][nt][0] * r0);
      ctxk[(size_t)(srow + 1) * HD + col] = f2bf(acc[blk][nt][1] * r1);
      ctxk[(size_t)(srow + 2) * HD + col] = f2bf(acc[blk][nt][2] * r2);
      ctxk[(size_t)(srow + 3) * HD + col] = f2bf(acc[blk][nt][3] * r3);
    }
  }
}

// ---------------- kernel 3: out = combine(ctxp) @ Wc + bc + x -------------
// R9/R10-validated grid-64 structure; A-tile staging combines the NKB
// key-slice partials (head kt => NKB scalar l-loads per row; exact for
// raw-exp softmax).
template<int NKB>
__global__ __launch_bounds__(256) void out_kernel(
    const unsigned short* __restrict__ ctxp,
    const float* __restrict__ lbuf,
    const unsigned short* __restrict__ WcT,
    const float* __restrict__ bc,
    const float* __restrict__ x,
    float* __restrict__ out)
{
  __shared__ unsigned short At[64 * 136];
  __shared__ unsigned short Bt[128 * 136];
  const int tid = threadIdx.x;
  const int s0 = blockIdx.x * 64;
  const int lane = tid & 63, w = tid >> 6;
  const int c = lane & 15, q4 = lane >> 4;

  f32x4 acc[8];
  for (int nt = 0; nt < 8; ++nt) acc[nt] = (f32x4){0.f, 0.f, 0.f, 0.f};

  for (int kt = 0; kt < 8; ++kt) {         // head kt
    __syncthreads();
    for (int i = 0; i < 4; ++i) {
      int ch = tid + i * 256;
      int row = ch >> 4, col8 = (ch & 15) * 8;
      const unsigned short* p0 = &ctxp[(size_t)(s0 + row) * HD + kt * 128 + col8];
      float lv[NKB], lsum = 0.f;
      for (int kb = 0; kb < NKB; ++kb) {
        lv[kb] = lbuf[(size_t)kb * NHEADS * SQ + (size_t)kt * SQ + s0 + row];
        lsum += lv[kb];
      }
      float ri = 1.f / lsum;
      float fv[8];
      for (int e = 0; e < 8; ++e) fv[e] = 0.f;
      for (int kb = 0; kb < NKB; ++kb) {
        u16x8 a = *(const u16x8*)(p0 + (size_t)kb * SQ * HD);
        float wgt = lv[kb] * ri;
        for (int e = 0; e < 8; ++e) fv[e] += wgt * b2f(a[e]);
      }
      u16x8 av;
      for (int e = 0; e < 8; ++e) av[e] = f2bf(fv[e]);
      *(u16x8*)&At[row * 136 + col8] = av;
    }
    for (int i = 0; i < 8; ++i) {
      int ch = tid + i * 256;
      int row = ch >> 4, col8 = (ch & 15) * 8;
      *(u16x8*)&Bt[row * 136 + col8] =
          *(const u16x8*)&WcT[row * HD + kt * 128 + col8];
    }
    __syncthreads();
    bf16x8 af[4];
    for (int kc = 0; kc < 4; ++kc)
      af[kc] = ld_bf8(&At[(w * 16 + c) * 136 + kc * 32 + q4 * 8]);
    for (int nt = 0; nt < 8; ++nt) {
      f32x4 a = acc[nt];
      for (int kc = 0; kc < 4; ++kc) {
        bf16x8 bf = ld_bf8(&Bt[(nt * 16 + c) * 136 + kc * 32 + q4 * 8]);
        a = __builtin_amdgcn_mfma_f32_16x16x32_bf16(af[kc], bf, a, 0, 0, 0);
      }
      acc[nt] = a;
    }
  }
  for (int nt = 0; nt < 8; ++nt) {
    float bb = bc[nt * 16 + c];
    for (int r = 0; r < 4; ++r) {
      int srow = s0 + w * 16 + q4 * 4 + r;
      int col = nt * 16 + c;
      out[srow * H + col] = acc[nt][r] + bb + x[srow * H + col];
    }
  }
}

extern "C" void kernel_launch(void* const* d_in, const int* in_sizes, int n_in,
                              void* d_out, int out_size, void* d_ws, size_t ws_size,
                              hipStream_t stream) {
  const float* x  = (const float*)d_in[0];
  const float* W1 = (const float*)d_in[1];
  const float* b1 = (const float*)d_in[2];
  const float* W2 = (const float*)d_in[3];
  const float* b2 = (const float*)d_in[4];
  const float* Wc = (const float*)d_in[5];
  const float* bc = (const float*)d_in[6];
  float* out = (float*)d_out;

  // NKB=3 needs 51,511,296 B (capacity PROVEN by R12's passing run);
  // NKB=2 needs 42,991,616 B (proven R9/R10). ws_size launch-invariant.
  const size_t NEED3 = (size_t)3 * NHEADS * SQ * H * 2
                     + (size_t)3 * SQ * HD * 2
                     + (size_t)3 * NHEADS * SQ * 4
                     + (size_t)3 * HD * H * 2;
  const int nkb = (ws_size >= NEED3) ? 3 : 2;

  char* ws = (char*)d_ws;
  unsigned short* q1bf = (unsigned short*)ws; ws += (size_t)NHEADS * SQ * H * 2;
  unsigned short* q2K  = (unsigned short*)ws; ws += (size_t)NHEADS * SQ * H * 2;
  unsigned short* q2VT = (unsigned short*)ws; ws += (size_t)NHEADS * SQ * H * 2;
  unsigned short* ctxp = (unsigned short*)ws; ws += (size_t)nkb * SQ * HD * 2;
  float*          lbuf = (float*)ws;          ws += (size_t)nkb * NHEADS * SQ * 4;
  unsigned short* W1T  = (unsigned short*)ws; ws += (size_t)HD * H * 2;
  unsigned short* W2T  = (unsigned short*)ws; ws += (size_t)HD * H * 2;
  unsigned short* WcT  = (unsigned short*)ws; ws += (size_t)HD * H * 2;

  prep_kernel<<<64, 256, 0, stream>>>(W1, W2, Wc, W1T, W2T, WcT);
  proj_kernel<<<512, 256, 0, stream>>>(x, b1, b2, W1T, W2T, q1bf, q2K, q2VT);
  if (nkb == 3) {
    flash_kernel<3><<<768, 256, 0, stream>>>(q1bf, q2K, q2VT, ctxp, lbuf);
    out_kernel<3><<<64, 256, 0, stream>>>(ctxp, lbuf, WcT, bc, x, out);
  } else {
    flash_kernel<2><<<512, 256, 0, stream>>>(q1bf, q2K, q2VT, ctxp, lbuf);
    out_kernel<2><<<64, 256, 0, stream>>>(ctxp, lbuf, WcT, bc, x, out);
  }
}